// Round 3
// baseline (121.464 us; speedup 1.0000x reference)
//
#include <hip/hip_runtime.h>
#include <hip/hip_cooperative_groups.h>
#include <math.h>

namespace cg = cooperative_groups;

#define NSAMP 524288              // 2^19 samples per channel
#define CHUNK 16                  // samples per thread
#define WGT 256                   // threads per workgroup
#define NWG 128                   // workgroups per channel
#define TOTWG (2 * NWG)           // 256 workgroups total
#define HIDDEN 16
#define LS 33                     // LDS row stride (conflict-free)

__device__ __forceinline__ float fast_tanh(float x) {
    float e = __expf(2.0f * x);
    return (e - 1.0f) / (e + 1.0f);
}

// (Mo,do) = (Ma,da) ∘ (Mb,db): apply b first, then a
__device__ __forceinline__ void compose5(const float* Ma, const float* da,
                                         const float* Mb, const float* db,
                                         float* Mo, float* dout) {
#pragma unroll
    for (int r = 0; r < 5; ++r) {
#pragma unroll
        for (int c = 0; c < 5; ++c) {
            float acc = 0.0f;
#pragma unroll
            for (int k = 0; k < 5; ++k) acc = fmaf(Ma[r*5+k], Mb[k*5+c], acc);
            Mo[r*5+c] = acc;
        }
        float acc = da[r];
#pragma unroll
        for (int k = 0; k < 5; ++k) acc = fmaf(Ma[r*5+k], db[k], acc);
        dout[r] = acc;
    }
}

__global__ void __launch_bounds__(WGT) k_fused(
    const float* __restrict__ X,
    const float* __restrict__ rate01,
    const float* __restrict__ phoff01,
    const float* __restrict__ W1,
    const float* __restrict__ b1,
    const float* __restrict__ W2,
    const float* __restrict__ b2,
    const float* __restrict__ amp,
    const float* __restrict__ bias_,
    const float* __restrict__ depth_,
    const float* __restrict__ g1p,
    const float* __restrict__ prevph,
    float* __restrict__ OUT,
    float* __restrict__ REC,
    float* __restrict__ WGS)
{
    cg::grid_group grid = cg::this_grid();
    __shared__ float sM[WGT * LS];    // per-thread inclusive records (phase B/D)
    __shared__ float aM[NWG * LS];    // aggregate scan buffer (phase C)

    const int w  = blockIdx.x;
    const int c  = w >> 7;            // NWG = 128
    const int wc = w & (NWG - 1);
    const int t  = threadIdx.x;
    const int b  = wc * WGT + t;      // block index within channel
    const long base = (long)c * NSAMP + (long)b * CHUNK;

    // ================= Phase A: coefficients + input, in registers =========
    const float two_pi = 6.28318530717958647692f;
    const float rate  = fmaf(rate01[0], 4.9f, 0.1f);
    const float w0    = two_pi * rate / 44100.0f;
    const float ab    = prevph[0] + (c ? phoff01[0] * two_pi : 0.0f);
    const float dscale = depth_[0] * 0.5f;
    const float g1    = g1p[0];
    const float b2v   = b2[0];
    const float ampv  = amp[0];
    const float biasv = bias_[0];

    float xv[CHUNK], pv[CHUNK], mm[CHUNK];
    {
        const float4* Xv = (const float4*)(X + base);
#pragma unroll
        for (int q = 0; q < CHUNK / 4; ++q) {
            float4 f = Xv[q];
            xv[q*4+0] = f.x; xv[q*4+1] = f.y; xv[q*4+2] = f.z; xv[q*4+3] = f.w;
        }
    }
#pragma unroll
    for (int k = 0; k < CHUNK; ++k) {
        float arg = fmaf(w0, (float)(b * CHUNK + k + 1), ab);
        pv[k] = ampv * cosf(arg);      // pv temporarily holds lfo
        mm[k] = b2v;
    }
#pragma unroll
    for (int j = 0; j < HIDDEN; ++j) {
        float w1j = W1[j], b1j = b1[j], w2j = W2[j];
#pragma unroll
        for (int k = 0; k < CHUNK; ++k) {
            float h = fast_tanh(fmaf(pv[k], w1j, b1j));
            mm[k] = fmaf(h, w2j, mm[k]);
        }
    }
#pragma unroll
    for (int k = 0; k < CHUNK; ++k) {
        float d = fmaf(dscale, 1.0f + mm[k], biasv);
        float td = __tanf(d);
        pv[k] = fast_tanh((1.0f - td) / (1.0f + td));
    }

    // ========== Phase B: block transform + intra-WG inclusive scan =========
    float v[6][5];                    // 5 basis vectors + zero-init input vec
#pragma unroll
    for (int j = 0; j < 6; ++j)
#pragma unroll
        for (int r = 0; r < 5; ++r) v[j][r] = (j == r) ? 1.0f : 0.0f;

#pragma unroll
    for (int k = 0; k < CHUNK; ++k) {
        float pp = pv[k], xx = xv[k];
#pragma unroll
        for (int j = 0; j < 6; ++j) {
            float xin = (j == 5) ? xx : 0.0f;
            float u0 = fmaf(g1, v[j][4], xin);
            float y0 = fmaf(pp, u0 - v[j][1], v[j][0]);
            float y1 = fmaf(pp, y0 - v[j][2], v[j][1]);
            float y2 = fmaf(pp, y1 - v[j][3], v[j][2]);
            float y3 = fmaf(pp, y2 - v[j][4], v[j][3]);
            v[j][0] = u0; v[j][1] = y0; v[j][2] = y1; v[j][3] = y2; v[j][4] = y3;
        }
    }

    float M[25], d[5];
#pragma unroll
    for (int j = 0; j < 5; ++j)
#pragma unroll
        for (int r = 0; r < 5; ++r) M[r*5+j] = v[j][r];
#pragma unroll
    for (int r = 0; r < 5; ++r) d[r] = v[5][r];

#pragma unroll
    for (int k = 0; k < 25; ++k) sM[t*LS + k] = M[k];
#pragma unroll
    for (int r = 0; r < 5; ++r) sM[t*LS + 25 + r] = d[r];
    __syncthreads();

    for (int off = 1; off < WGT; off <<= 1) {
        float pM[25], pd[5];
        bool act = (t >= off);
        if (act) {
#pragma unroll
            for (int k = 0; k < 25; ++k) pM[k] = sM[(t-off)*LS + k];
#pragma unroll
            for (int r = 0; r < 5; ++r) pd[r] = sM[(t-off)*LS + 25 + r];
        }
        __syncthreads();
        if (act) {
            float Mn[25], dn[5];
            compose5(M, d, pM, pd, Mn, dn);
#pragma unroll
            for (int k = 0; k < 25; ++k) { M[k] = Mn[k]; sM[t*LS + k] = Mn[k]; }
#pragma unroll
            for (int r = 0; r < 5; ++r) { d[r] = dn[r]; sM[t*LS + 25 + r] = dn[r]; }
        }
        __syncthreads();
    }

    // WG aggregate -> global
    if (t == WGT - 1) {
        float* rp = REC + (long)w * 32;
#pragma unroll
        for (int k = 0; k < 25; ++k) rp[k] = M[k];
#pragma unroll
        for (int r = 0; r < 5; ++r) rp[25 + r] = d[r];
    }
    __threadfence();
    grid.sync();

    // ===== Phase C: one WG per channel scans the 128 aggregates ============
    if (wc == 0) {
        float Ms[25], ds[5];
        const bool act0 = (t < NWG);
        if (act0) {
            const float* rp = REC + (long)(c * NWG + t) * 32;
#pragma unroll
            for (int k = 0; k < 25; ++k) { Ms[k] = rp[k]; aM[t*LS + k] = Ms[k]; }
#pragma unroll
            for (int r = 0; r < 5; ++r) { ds[r] = rp[25 + r]; aM[t*LS + 25 + r] = ds[r]; }
        }
        __syncthreads();
        for (int off = 1; off < NWG; off <<= 1) {
            float pM[25], pd[5];
            bool act = act0 && (t >= off);
            if (act) {
#pragma unroll
                for (int k = 0; k < 25; ++k) pM[k] = aM[(t-off)*LS + k];
#pragma unroll
                for (int r = 0; r < 5; ++r) pd[r] = aM[(t-off)*LS + 25 + r];
            }
            __syncthreads();
            if (act) {
                float Mn[25], dn[5];
                compose5(Ms, ds, pM, pd, Mn, dn);
#pragma unroll
                for (int k = 0; k < 25; ++k) { Ms[k] = Mn[k]; aM[t*LS + k] = Mn[k]; }
#pragma unroll
                for (int r = 0; r < 5; ++r) { ds[r] = dn[r]; aM[t*LS + 25 + r] = dn[r]; }
            }
            __syncthreads();
        }
        if (act0) {
            // exclusive prefix applied to zero initial state -> d-part only
#pragma unroll
            for (int r = 0; r < 5; ++r)
                WGS[(c * NWG + t) * 8 + r] = (t == 0) ? 0.0f : aM[(t-1)*LS + 25 + r];
        }
    }
    __threadfence();
    grid.sync();

    // ====== Phase D: apply prefix, run recursion from registers, emit ======
    float sw[5];
#pragma unroll
    for (int r = 0; r < 5; ++r) sw[r] = WGS[(c * NWG + wc) * 8 + r];

    float s0, s1, s2, s3, s4;
    if (t == 0) {
        s0 = sw[0]; s1 = sw[1]; s2 = sw[2]; s3 = sw[3]; s4 = sw[4];
    } else {
        const float* rp = &sM[(t-1) * LS];   // neighbor's inclusive record (LDS)
        float s[5];
#pragma unroll
        for (int r = 0; r < 5; ++r) {
            float acc = rp[25 + r];
#pragma unroll
            for (int j = 0; j < 5; ++j) acc = fmaf(rp[r*5 + j], sw[j], acc);
            s[r] = acc;
        }
        s0 = s[0]; s1 = s[1]; s2 = s[2]; s3 = s[3]; s4 = s[4];
    }

    float4* Ov = (float4*)(OUT + base);
#pragma unroll
    for (int q = 0; q < CHUNK / 4; ++q) {
        float oa[4];
#pragma unroll
        for (int ii = 0; ii < 4; ++ii) {
            float pp = pv[q*4 + ii], xx = xv[q*4 + ii];
            float u0 = fmaf(g1, s4, xx);
            float y0 = fmaf(pp, u0 - s1, s0);
            float y1 = fmaf(pp, y0 - s2, s1);
            float y2 = fmaf(pp, y1 - s3, s2);
            float y3 = fmaf(pp, y2 - s4, s3);
            s0 = u0; s1 = y0; s2 = y1; s3 = y2; s4 = y3;
            oa[ii] = 0.5f * (xx + y3);
        }
        float4 o; o.x = oa[0]; o.y = oa[1]; o.z = oa[2]; o.w = oa[3];
        Ov[q] = o;
    }
}

extern "C" void kernel_launch(void* const* d_in, const int* in_sizes, int n_in,
                              void* d_out, int out_size, void* d_ws, size_t ws_size,
                              hipStream_t stream) {
    const float* x     = (const float*)d_in[0];
    const float* rate  = (const float*)d_in[1];
    const float* phoff = (const float*)d_in[2];
    const float* W1    = (const float*)d_in[3];
    const float* b1    = (const float*)d_in[4];
    const float* W2    = (const float*)d_in[5];
    const float* b2    = (const float*)d_in[6];
    const float* amp   = (const float*)d_in[7];
    const float* bias_ = (const float*)d_in[8];
    const float* depth = (const float*)d_in[9];
    const float* g1    = (const float*)d_in[10];
    const float* pph   = (const float*)d_in[11];
    float* out = (float*)d_out;

    float* REC = (float*)d_ws;             // TOTWG*32 floats (32 KB)
    float* WGS = REC + (long)TOTWG * 32;   // TOTWG*8 floats  (8 KB)

    void* args[] = {
        (void*)&x, (void*)&rate, (void*)&phoff,
        (void*)&W1, (void*)&b1, (void*)&W2, (void*)&b2,
        (void*)&amp, (void*)&bias_, (void*)&depth,
        (void*)&g1, (void*)&pph,
        (void*)&out, (void*)&REC, (void*)&WGS
    };
    hipLaunchCooperativeKernel((const void*)k_fused, dim3(TOTWG), dim3(WGT),
                               args, 0, stream);
}

// Round 4
// 69.559 us; speedup vs baseline: 1.7462x; 1.7462x over previous
//
#include <hip/hip_runtime.h>
#include <hip/hip_cooperative_groups.h>
#include <math.h>

namespace cg = cooperative_groups;

#define NSAMP 524288              // 2^19 samples per channel
#define CHUNK 16                  // samples per thread
#define WGT 256                   // threads per workgroup
#define NWGC 128                  // workgroups per channel
#define TOTWG 256                 // total workgroups (1 per CU)
#define HIDDEN 16
#define LS 33                     // LDS row stride (conflict-free)
#define NTAB 512                  // p(theta) lookup table size

__device__ __forceinline__ float fast_tanh(float x) {
    float e = __expf(2.0f * x);
    return (e - 1.0f) / (e + 1.0f);
}

// (Mo,do) = (Ma,da) ∘ (Mb,db): apply b first, then a
__device__ __forceinline__ void compose5(const float* Ma, const float* da,
                                         const float* Mb, const float* db,
                                         float* Mo, float* dout) {
#pragma unroll
    for (int r = 0; r < 5; ++r) {
#pragma unroll
        for (int c = 0; c < 5; ++c) {
            float acc = 0.0f;
#pragma unroll
            for (int k = 0; k < 5; ++k) acc = fmaf(Ma[r*5+k], Mb[k*5+c], acc);
            Mo[r*5+c] = acc;
        }
        float acc = da[r];
#pragma unroll
        for (int k = 0; k < 5; ++k) acc = fmaf(Ma[r*5+k], db[k], acc);
        dout[r] = acc;
    }
}

__global__ void __launch_bounds__(WGT, 1) k_fused(
    const float* __restrict__ X,
    const float* __restrict__ rate01,
    const float* __restrict__ phoff01,
    const float* __restrict__ W1,
    const float* __restrict__ b1,
    const float* __restrict__ W2,
    const float* __restrict__ b2,
    const float* __restrict__ amp,
    const float* __restrict__ bias_,
    const float* __restrict__ depth_,
    const float* __restrict__ g1p,
    const float* __restrict__ prevph,
    float* __restrict__ OUT,
    float* __restrict__ REC)
{
    cg::grid_group grid = cg::this_grid();
    __shared__ float Tp[NTAB];        // p(theta) table, theta in revolutions
    __shared__ float sM[WGT * LS];    // per-thread inclusive records
    __shared__ float aM[NWGC * LS];   // aggregate scan buffer

    const int w  = blockIdx.x;
    const int c  = w >> 7;            // NWGC = 128
    const int wc = w & (NWGC - 1);
    const int t  = threadIdx.x;
    const int b  = wc * WGT + t;      // block index within channel
    const long base = (long)c * NSAMP + (long)b * CHUNK;

    const float two_pi = 6.28318530717958647692f;
    const float rate   = fmaf(rate01[0], 4.9f, 0.1f);
    const float w0rev  = rate / 44100.0f;                      // rev per sample
    const float phrev  = prevph[0] * (1.0f / two_pi) + (c ? phoff01[0] : 0.0f);
    const float dscale = depth_[0] * 0.5f;
    const float g1     = g1p[0];
    const float b2v    = b2[0];
    const float ampv   = amp[0];
    const float biasv  = bias_[0];

    // ============ Phase 0: build p(theta) table (2 entries/thread) =========
#pragma unroll
    for (int e = 0; e < NTAB / WGT; ++e) {
        int j = t + e * WGT;
        float lfo = ampv * __cosf((float)j * (two_pi / (float)NTAB));
        float m = b2v;
#pragma unroll
        for (int jj = 0; jj < HIDDEN; ++jj) {
            float h = fast_tanh(fmaf(lfo, W1[jj], b1[jj]));
            m = fmaf(h, W2[jj], m);
        }
        float dd = fmaf(dscale, 1.0f + m, biasv);
        float td = __tanf(dd);
        Tp[j] = fast_tanh((1.0f - td) / (1.0f + td));
    }
    __syncthreads();

    // ============ Phase A: per-sample coefficient via table lookup =========
    float pv[CHUNK];
#pragma unroll
    for (int k = 0; k < CHUNK; ++k) {
        float ph = fmaf(w0rev, (float)(b * CHUNK + k + 1), phrev);
        float u = (ph - floorf(ph)) * (float)NTAB;
        int i0 = ((int)u) & (NTAB - 1);
        float f = u - floorf(u);
        int i1 = (i0 + 1) & (NTAB - 1);
        float t0 = Tp[i0];
        pv[k] = fmaf(f, Tp[i1] - t0, t0);
    }

    // ========== Phase B: block transform + intra-WG inclusive scan =========
    float v[6][5];                    // 5 basis vectors + zero-init input vec
#pragma unroll
    for (int j = 0; j < 6; ++j)
#pragma unroll
        for (int r = 0; r < 5; ++r) v[j][r] = (j == r) ? 1.0f : 0.0f;

    {
        const float4* Xv = (const float4*)(X + base);
#pragma unroll
        for (int q = 0; q < CHUNK / 4; ++q) {
            float4 x4 = Xv[q];
            float xa[4] = {x4.x, x4.y, x4.z, x4.w};
#pragma unroll
            for (int ii = 0; ii < 4; ++ii) {
                float pp = pv[q*4 + ii], xx = xa[ii];
#pragma unroll
                for (int j = 0; j < 6; ++j) {
                    float xin = (j == 5) ? xx : 0.0f;
                    float u0 = fmaf(g1, v[j][4], xin);
                    float y0 = fmaf(pp, u0 - v[j][1], v[j][0]);
                    float y1 = fmaf(pp, y0 - v[j][2], v[j][1]);
                    float y2 = fmaf(pp, y1 - v[j][3], v[j][2]);
                    float y3 = fmaf(pp, y2 - v[j][4], v[j][3]);
                    v[j][0] = u0; v[j][1] = y0; v[j][2] = y1; v[j][3] = y2; v[j][4] = y3;
                }
            }
        }
    }

    float M[25], d[5];
#pragma unroll
    for (int j = 0; j < 5; ++j)
#pragma unroll
        for (int r = 0; r < 5; ++r) M[r*5+j] = v[j][r];
#pragma unroll
    for (int r = 0; r < 5; ++r) d[r] = v[5][r];

#pragma unroll
    for (int k = 0; k < 25; ++k) sM[t*LS + k] = M[k];
#pragma unroll
    for (int r = 0; r < 5; ++r) sM[t*LS + 25 + r] = d[r];
    __syncthreads();

    for (int off = 1; off < WGT; off <<= 1) {
        float pM[25], pd[5];
        bool act = (t >= off);
        if (act) {
#pragma unroll
            for (int k = 0; k < 25; ++k) pM[k] = sM[(t-off)*LS + k];
#pragma unroll
            for (int r = 0; r < 5; ++r) pd[r] = sM[(t-off)*LS + 25 + r];
        }
        __syncthreads();
        if (act) {
            float Mn[25], dn[5];
            compose5(M, d, pM, pd, Mn, dn);
#pragma unroll
            for (int k = 0; k < 25; ++k) { M[k] = Mn[k]; sM[t*LS + k] = Mn[k]; }
#pragma unroll
            for (int r = 0; r < 5; ++r) { d[r] = dn[r]; sM[t*LS + 25 + r] = dn[r]; }
        }
        __syncthreads();
    }

    // WG aggregate -> global
    if (t == WGT - 1) {
        float* rp = REC + (long)w * 32;
#pragma unroll
        for (int k = 0; k < 25; ++k) rp[k] = M[k];
#pragma unroll
        for (int r = 0; r < 5; ++r) rp[25 + r] = d[r];
        rp[30] = 0.0f; rp[31] = 0.0f;
    }
    __threadfence();
    grid.sync();

    // ==== Phase C: every WG redundantly scans its channel's aggregates =====
    float sw[5];
    {
        float Ms[25], ds[5];
        const bool act0 = (t < NWGC);
        if (act0) {
            const float4* rv = (const float4*)(REC + (long)(c * NWGC + t) * 32);
            float r[32];
#pragma unroll
            for (int q = 0; q < 8; ++q) {
                float4 f = rv[q];
                r[q*4] = f.x; r[q*4+1] = f.y; r[q*4+2] = f.z; r[q*4+3] = f.w;
            }
#pragma unroll
            for (int k = 0; k < 25; ++k) { Ms[k] = r[k]; aM[t*LS + k] = Ms[k]; }
#pragma unroll
            for (int k = 0; k < 5; ++k) { ds[k] = r[25 + k]; aM[t*LS + 25 + k] = ds[k]; }
        }
        __syncthreads();
        for (int off = 1; off < NWGC; off <<= 1) {
            float pM[25], pd[5];
            bool act = act0 && (t >= off);
            if (act) {
#pragma unroll
                for (int k = 0; k < 25; ++k) pM[k] = aM[(t-off)*LS + k];
#pragma unroll
                for (int k = 0; k < 5; ++k) pd[k] = aM[(t-off)*LS + 25 + k];
            }
            __syncthreads();
            if (act) {
                float Mn[25], dn[5];
                compose5(Ms, ds, pM, pd, Mn, dn);
#pragma unroll
                for (int k = 0; k < 25; ++k) { Ms[k] = Mn[k]; aM[t*LS + k] = Mn[k]; }
#pragma unroll
                for (int k = 0; k < 5; ++k) { ds[k] = dn[k]; aM[t*LS + 25 + k] = dn[k]; }
            }
            __syncthreads();
        }
        // entry state of this WG: exclusive prefix of aggregates applied to 0
#pragma unroll
        for (int r = 0; r < 5; ++r)
            sw[r] = (wc == 0) ? 0.0f : aM[(wc-1)*LS + 25 + r];
    }

    // ====== Phase D: apply prefix, run recursion, emit output ==============
    float s0, s1, s2, s3, s4;
    if (t == 0) {
        s0 = sw[0]; s1 = sw[1]; s2 = sw[2]; s3 = sw[3]; s4 = sw[4];
    } else {
        const float* rp = &sM[(t-1) * LS];   // neighbor's inclusive record
        float s[5];
#pragma unroll
        for (int r = 0; r < 5; ++r) {
            float acc = rp[25 + r];
#pragma unroll
            for (int j = 0; j < 5; ++j) acc = fmaf(rp[r*5 + j], sw[j], acc);
            s[r] = acc;
        }
        s0 = s[0]; s1 = s[1]; s2 = s[2]; s3 = s[3]; s4 = s[4];
    }

    {
        const float4* Xv = (const float4*)(X + base);
        float4* Ov = (float4*)(OUT + base);
#pragma unroll
        for (int q = 0; q < CHUNK / 4; ++q) {
            float4 x4 = Xv[q];
            float xa[4] = {x4.x, x4.y, x4.z, x4.w};
            float oa[4];
#pragma unroll
            for (int ii = 0; ii < 4; ++ii) {
                float pp = pv[q*4 + ii], xx = xa[ii];
                float u0 = fmaf(g1, s4, xx);
                float y0 = fmaf(pp, u0 - s1, s0);
                float y1 = fmaf(pp, y0 - s2, s1);
                float y2 = fmaf(pp, y1 - s3, s2);
                float y3 = fmaf(pp, y2 - s4, s3);
                s0 = u0; s1 = y0; s2 = y1; s3 = y2; s4 = y3;
                oa[ii] = 0.5f * (xx + y3);
            }
            float4 o; o.x = oa[0]; o.y = oa[1]; o.z = oa[2]; o.w = oa[3];
            Ov[q] = o;
        }
    }
}

extern "C" void kernel_launch(void* const* d_in, const int* in_sizes, int n_in,
                              void* d_out, int out_size, void* d_ws, size_t ws_size,
                              hipStream_t stream) {
    const float* x     = (const float*)d_in[0];
    const float* rate  = (const float*)d_in[1];
    const float* phoff = (const float*)d_in[2];
    const float* W1    = (const float*)d_in[3];
    const float* b1    = (const float*)d_in[4];
    const float* W2    = (const float*)d_in[5];
    const float* b2    = (const float*)d_in[6];
    const float* amp   = (const float*)d_in[7];
    const float* bias_ = (const float*)d_in[8];
    const float* depth = (const float*)d_in[9];
    const float* g1    = (const float*)d_in[10];
    const float* pph   = (const float*)d_in[11];
    float* out = (float*)d_out;

    float* REC = (float*)d_ws;             // TOTWG*32 floats (32 KB)

    void* args[] = {
        (void*)&x, (void*)&rate, (void*)&phoff,
        (void*)&W1, (void*)&b1, (void*)&W2, (void*)&b2,
        (void*)&amp, (void*)&bias_, (void*)&depth,
        (void*)&g1, (void*)&pph,
        (void*)&out, (void*)&REC
    };
    hipLaunchCooperativeKernel((const void*)k_fused, dim3(TOTWG), dim3(WGT),
                               args, 0, stream);
}